// Round 10
// baseline (197.618 us; speedup 1.0000x reference)
//
#include <hip/hip_runtime.h>

typedef __bf16 bf16x8 __attribute__((ext_vector_type(8)));
typedef float f32x16 __attribute__((ext_vector_type(16)));
typedef unsigned short ushort8 __attribute__((ext_vector_type(8)));

__device__ __forceinline__ unsigned short f2bf(float f) {
  unsigned int u = __builtin_bit_cast(unsigned int, f);
  u += 0x7FFFu + ((u >> 16) & 1u);   // RNE
  return (unsigned short)(u >> 16);
}

// COEF[a][du][u] = weight of W-tap u on x-offset du for output phase a
// (interior-exact; borders p==0 / q==0 recomputed by the border path).
__constant__ float COEF[2][3][3] = {
    {{0.25f, 0.00f, 0.00f},
     {0.75f, 0.75f, 0.25f},
     {0.00f, 0.25f, 0.75f}},
    {{0.75f, 0.25f, 0.00f},
     {0.25f, 0.75f, 0.75f},
     {0.00f, 0.00f, 0.25f}}
};

// Pack phase-blended weights into 32x32x16 MFMA B-fragment layout, bf16.
// fi = (((cblk*3+dv)*2+ksub)*3+du)*4 + nt32  (288 frags/phase).
// Frag: lane l holds B[k][oc = nt32*32 + (l&31)],
// k -> c = cblk*32 + ksub*16 + (l>>5)*8 + j.
__global__ void pack_weights(const float* __restrict__ w, unsigned short* __restrict__ pw) {
  const int fi = blockIdx.x;
  const int l = threadIdx.x;
  const int nt32 = fi & 3;
  int t = fi >> 2;
  const int du = t % 3; t /= 3;
  const int ksub = t & 1; t >>= 1;
  const int dv = t % 3;
  const int cblk = t / 3;
  const int c0 = cblk * 32 + ksub * 16 + ((l >> 5) << 3);
  const int oc = nt32 * 32 + (l & 31);
  float accp[4][8];
#pragma unroll
  for (int ph = 0; ph < 4; ++ph)
#pragma unroll
    for (int j = 0; j < 8; ++j) accp[ph][j] = 0.0f;
#pragma unroll
  for (int u = 0; u < 3; ++u)
#pragma unroll
    for (int v = 0; v < 3; ++v) {
      const float ra0 = COEF[0][du][u], ra1 = COEF[1][du][u];
      const float cb0 = COEF[0][dv][v], cb1 = COEF[1][dv][v];
      const float c00 = ra0 * cb0, c01 = ra0 * cb1, c10 = ra1 * cb0, c11 = ra1 * cb1;
#pragma unroll
      for (int j = 0; j < 8; ++j) {
        const float wv = w[((u * 3 + v) * 128 + c0 + j) * 128 + oc];
        accp[0][j] += c00 * wv;
        accp[1][j] += c01 * wv;
        accp[2][j] += c10 * wv;
        accp[3][j] += c11 * wv;
      }
    }
#pragma unroll
  for (int ph = 0; ph < 4; ++ph) {
    ushort8 o;
#pragma unroll
    for (int j = 0; j < 8; ++j) o[j] = f2bf(accp[ph][j]);
    *(ushort8*)(pw + (((ph * 288 + fi) * 64 + l) << 3)) = o;
  }
}

// Single fused launch: blocks 0..511 border fixup; 512..1535 main tiles.
// Main: out tile 8 rows x 64 cols x 128 oc, 512 thr, 8 waves (a,b,nhalf).
// Wave = 4 m-tiles (1 x-row x 32 x-cols) x 2 n-tiles (32 oc), 32x32x16 MFMA,
// acc[4][2] f32x16 (128 AGPR). x-tile 7x35x128 bf16 (62.7 KB). af[6] du-ring.
__global__ __launch_bounds__(512, 2) void fused_all(
    const float* __restrict__ x, const unsigned short* __restrict__ pw,
    const float* __restrict__ w, const float* __restrict__ bias,
    float* __restrict__ out) {
  __shared__ __align__(16) char smem[7 * 35 * 256];  // 62,720 B

  const int bid = blockIdx.x;
  const int tid = threadIdx.x;

  if (bid < 512) {
    // ================= BORDER PATH (R8 verbatim) =================
    const int chunk = bid & 31;
    const int type = (bid >> 5) & 1;  // 0: row p=0 (all q); 1: col q=0 (p>=1)
    const int bi = bid >> 6;
    const int base0 = chunk * 8;
    const float* xb = x + bi * (128 * 128 * 128);

    float* yw = (float*)smem;                    // [2][10][128] = 10,240 B
    float* part = (float*)(smem + 16384);        // [8][8][128]  = 32,768 B

    {
      const int c = tid & 127;
      const int sub = tid >> 7;  // 0..3
      for (int k = sub; k < 20; k += 4) {
        const int f = k / 10;
        const int ws = k - f * 10;
        const int t = base0 - 1 + ws;
        float val = 0.0f;
        if ((unsigned)t < 256u) {
          const int t0 = t >> 1;
          const float hA0 = (t & 1) ? 0.25f : 0.75f;
          const float hA1 = 1.0f - hA0;
          const float hF0 = f ? 0.25f : 0.75f;
          const float hF1 = 1.0f - hF0;
          const bool ok = (t0 + 1) < 128;
          if (type == 0) {  // fixed x-rows 0,1 ; moving col t
            const float v00 = xb[t0 * 128 + c];
            const float v01 = ok ? xb[(t0 + 1) * 128 + c] : 0.0f;
            const float v10 = xb[(128 + t0) * 128 + c];
            const float v11 = ok ? xb[(128 + t0 + 1) * 128 + c] : 0.0f;
            val = hF0 * (hA0 * v00 + hA1 * v01) + hF1 * (hA0 * v10 + hA1 * v11);
          } else {          // fixed x-cols 0,1 ; moving row t
            const float v00 = xb[(t0 * 128) * 128 + c];
            const float v01 = xb[(t0 * 128 + 1) * 128 + c];
            const float v10 = ok ? xb[((t0 + 1) * 128) * 128 + c] : 0.0f;
            const float v11 = ok ? xb[((t0 + 1) * 128 + 1) * 128 + c] : 0.0f;
            val = hA0 * (hF0 * v00 + hF1 * v01) + hA1 * (hF0 * v10 + hF1 * v11);
          }
        }
        yw[(f * 10 + ws) * 128 + c] = val;
      }
    }
    __syncthreads();

    const int wv = tid >> 6;
    const int oc0 = (tid & 63) * 2;
    const int cbase = wv * 16;

    float acc[8][2] = {};
#pragma unroll 1
    for (int cc = 0; cc < 16; ++cc) {
      float yr[2][10];
#pragma unroll
      for (int f = 0; f < 2; ++f)
#pragma unroll
        for (int ws = 0; ws < 10; ++ws)
          yr[f][ws] = yw[(f * 10 + ws) * 128 + cbase + cc];
#pragma unroll
      for (int tf = 0; tf < 2; ++tf) {
#pragma unroll
        for (int tb = 0; tb < 3; ++tb) {
          const int uu = (type == 0) ? (tf + 1) : tb;
          const int vv = (type == 0) ? tb : (tf + 1);
          const float2 w2 = *(const float2*)(
              w + ((uu * 3 + vv) * 128 + cbase + cc) * 128 + oc0);
#pragma unroll
          for (int pos = 0; pos < 8; ++pos) {
            const float yv = yr[tf][pos + tb];
            acc[pos][0] += yv * w2.x;
            acc[pos][1] += yv * w2.y;
          }
        }
      }
    }

#pragma unroll
    for (int pos = 0; pos < 8; ++pos)
      *(float2*)(part + (wv * 8 + pos) * 128 + oc0) = *(float2*)acc[pos];
    __syncthreads();

    const int pos = tid >> 6;
    const int ocp = (tid & 63) * 2;
    float s0 = 0.0f, s1 = 0.0f;
#pragma unroll
    for (int w8 = 0; w8 < 8; ++w8) {
      const float2 v = *(const float2*)(part + (w8 * 8 + pos) * 128 + ocp);
      s0 += v.x; s1 += v.y;
    }
    const int posg = base0 + pos;
    if (!(type == 1 && posg == 0)) {
      const int p = (type == 0) ? 0 : posg;
      const int q = (type == 0) ? posg : 0;
      const float2 b2 = *(const float2*)(bias + ocp);
      float2 r; r.x = s0 + b2.x; r.y = s1 + b2.y;
      *(float2*)(out + bi * (256 * 256 * 128) + (p * 256 + q) * 128 + ocp) = r;
    }
    return;
  }

  // ================= MAIN PATH =================
  char* xlds = smem;
  const int o = bid - 512;
  const int blk = (o & 7) * 128 + (o >> 3);  // bijective XCD swizzle (1024 % 8 == 0)
  const int bimg = blk >> 7;
  const int it = (blk >> 2) & 31;  // 32 row-tiles of 8 out rows
  const int jt = blk & 3;          // 4 col-tiles of 64 out cols
  const int I0 = it * 4, J0 = jt * 32;  // x-space origin
  const float* xb = x + bimg * (128 * 128 * 128);

  const int lane = tid & 63;
  const int l31 = lane & 31;
  const int khalf = lane >> 5;   // 0..1 (k-half of 32-c block)
  const int wid = tid >> 6;      // 8 waves
  const int a = (wid >> 2) & 1;  // row phase
  const int b = (wid >> 1) & 1;  // col phase
  const int nh = wid & 1;        // oc half
  const int ph = a * 2 + b;

  const char* pwb = (const char*)pw + ph * 294912 + (nh * 2) * 1024 + lane * 16;

#define LOADB(buf, gg_, du_)                                          \
  do {                                                                \
    const char* bp_ = pwb + (((gg_) * 3 + (du_)) << 12);              \
    buf[0] = *(const bf16x8*)(bp_);                                   \
    buf[1] = *(const bf16x8*)(bp_ + 1024);                            \
  } while (0)

  bf16x8 b0[2], b1[2], b2[2];
  LOADB(b0, 0, 0);  // prologue prefetch; completes under the stage barrier

  // ---- Stage x tile: rows I0-1..I0+5, cols J0-1..J0+33 ----
  for (int idx = tid; idx < 7 * 35 * 16; idx += 512) {
    const int cp = idx & 15;
    const int pos = idx >> 4;
    const int xr = pos / 35;
    const int xc = pos - xr * 35;
    const int gi = I0 - 1 + xr;
    const int gj = J0 - 1 + xc;
    ushort8 u8 = {};
    if (((unsigned)gi < 128u) && ((unsigned)gj < 128u)) {
      const float* p = xb + ((gi << 7) + gj) * 128 + (cp << 3);
      const float4 A = *(const float4*)p;
      const float4 Bv = *(const float4*)(p + 4);
      u8[0] = f2bf(A.x); u8[1] = f2bf(A.y); u8[2] = f2bf(A.z); u8[3] = f2bf(A.w);
      u8[4] = f2bf(Bv.x); u8[5] = f2bf(Bv.y); u8[6] = f2bf(Bv.z); u8[7] = f2bf(Bv.w);
    }
    int byte = (pos << 8) + (cp << 4);
    byte ^= (pos & 7) << 4;  // bank swizzle (write side)
    *(ushort8*)(xlds + byte) = u8;
  }
  __syncthreads();

  f32x16 acc[4][2] = {};
  const int colpart = l31 + b;

#define AREAD(rr, dv_, kbyte_)                                        \
  do {                                                                \
    const int posa = (a + (rr)) * 35 + colpart + (dv_);               \
    int byte_ = (posa << 8) + (kbyte_);                               \
    byte_ ^= (posa & 7) << 4;  /* read-side swizzle */                \
    af[rr] = *(const bf16x8*)(xlds + byte_);                          \
  } while (0)

#define MFMAS(du_, buf)                                               \
  do {                                                                \
    __builtin_amdgcn_s_setprio(1);                                    \
    _Pragma("unroll") for (int mt = 0; mt < 4; ++mt)                  \
        _Pragma("unroll") for (int n = 0; n < 2; ++n)                 \
            acc[mt][n] = __builtin_amdgcn_mfma_f32_32x32x16_bf16(     \
                af[(du_) + mt], buf[n], acc[mt][n], 0, 0, 0);         \
    __builtin_amdgcn_s_setprio(0);                                    \
  } while (0)

#pragma unroll 1
  for (int gg = 0; gg < 24; ++gg) {
    const int gd = gg >> 1;          // cblk*3 + dv
    const int ksub = gg & 1;
    const int cblk = gd / 3;
    const int dv = gd - cblk * 3;
    const int kbyte = cblk * 64 + ksub * 32 + (khalf << 4);

    bf16x8 af[6];
    AREAD(0, dv, kbyte); AREAD(1, dv, kbyte); AREAD(2, dv, kbyte);
    AREAD(3, dv, kbyte); AREAD(4, dv, kbyte); AREAD(5, dv, kbyte);

    LOADB(b1, gg, 1);
    MFMAS(0, b0);
    LOADB(b2, gg, 2);
    MFMAS(1, b1);
    {
      const int gn = (gg < 23) ? (gg + 1) : 23;
      LOADB(b0, gn, 0);
    }
    MFMAS(2, b2);
  }
#undef AREAD
#undef MFMAS
#undef LOADB

  // ---- Epilogue: C/D col=lane&31 (oc), row=(reg&3)+8*(reg>>2)+4*(lane>>5)
  //      (row = j, the x-col index). Border stores owned by border path. ----
  float bv[2];
  bv[0] = bias[nh * 64 + l31];
  bv[1] = bias[nh * 64 + 32 + l31];
  float* ob = out + bimg * (256 * 256 * 128) + nh * 64 + l31;
#pragma unroll
  for (int mt = 0; mt < 4; ++mt) {
    const int p = it * 8 + 2 * mt + a;
    if (p == 0) continue;  // wave-uniform
#pragma unroll
    for (int reg = 0; reg < 16; ++reg) {
      const int row = (reg & 3) + 8 * (reg >> 2) + 4 * khalf;
      const int q = jt * 64 + 2 * row + b;
      if (q == 0) continue;  // diverges only at jt==0,b==0,reg==0 for khalf==0
      float* orow = ob + (p * 256 + q) * 128;
      orow[0]  = acc[mt][0][reg] + bv[0];
      orow[32] = acc[mt][1][reg] + bv[1];
    }
  }
}

extern "C" void kernel_launch(void* const* d_in, const int* in_sizes, int n_in,
                              void* d_out, int out_size, void* d_ws, size_t ws_size,
                              hipStream_t stream) {
  const float* x = (const float*)d_in[0];
  const float* w = (const float*)d_in[1];
  const float* bias = (const float*)d_in[2];
  float* out = (float*)d_out;
  unsigned short* pw = (unsigned short*)d_ws;  // 1,179,648 B used

  pack_weights<<<dim3(288), dim3(64), 0, stream>>>(w, pw);
  fused_all<<<dim3(1536), dim3(512), 0, stream>>>(x, pw, w, bias, out);
}